// Round 4
// baseline (129.687 us; speedup 1.0000x reference)
//
#include <hip/hip_runtime.h>
#include <math.h>

// floss: weighted BCE with per-batch argmax-centroid weights.
// input/target: [256, 1, 224, 224] fp32. Output: scalar fp32 mean.
//
// R4: full-grid parallelism for BOTH phases (R3's k1 was capped at 256
// blocks = 1 block/CU and serialized ahead of k2):
//   k1 stats:  1024 blocks (4/image) x 448 thr — per-quarter branchless
//              (max, cnt, sum_i, sum_j) partials -> ws as float4
//   k2 bce:    1024 blocks (4/image) x 448 thr — merges its image's 4 stat
//              tuples inline (16 floats), then log2-domain weighted BCE over
//              its quarter, one atomicAdd per block into out
// Quarter = 3136 quads = exactly 7 grid-stride iterations of 448 threads.

#define WIMG 224
#define WW (WIMG * WIMG)        // 50176
#define NQ (WW / 4)             // 12544 quads; 56 quads/row
#define NB 256
#define NPARTB 4                // blocks per image
#define QPB (NQ / NPARTB)       // 3136 quads per block
#define NTHR 448                // 7 waves; QPB/NTHR == 7 exactly
#define NBLK (NB * NPARTB)      // 1024
#define LN2 0.69314718055994530942f
#define CLAMP2 (-144.269504088896340736f)   // -100 / ln2 (log2-domain clamp)

__global__ __launch_bounds__(NTHR) void stats_kernel(
    const float* __restrict__ target, float4* __restrict__ stats)
{
    const int blk  = blockIdx.x;
    const int b    = blk >> 2;
    const int part = blk & 3;
    const int tid  = threadIdx.x;
    const float4* __restrict__ t4 = (const float4*)(target + (size_t)b * WW);
    const int qbase = part * QPB;

    float m = -1.0f, cnt = 0.0f, si = 0.0f, sj = 0.0f;
    #pragma unroll
    for (int it = 0; it < QPB / NTHR; ++it) {
        int q  = qbase + it * NTHR + tid;
        float4 v = t4[q];
        int i  = q / 56;
        int j0 = (q - i * 56) * 4;
        float fi = (float)i;
        float vv[4] = {v.x, v.y, v.z, v.w};
        #pragma unroll
        for (int k = 0; k < 4; ++k) {
            float val = vv[k];
            float fj  = (float)(j0 + k);
            bool gt = val > m;
            bool eq = val == m;
            cnt = gt ? 1.0f : (cnt + (eq ? 1.0f : 0.0f));
            si  = gt ? fi   : (si  + (eq ? fi   : 0.0f));
            sj  = gt ? fj   : (sj  + (eq ? fj   : 0.0f));
            m   = fmaxf(m, val);
        }
    }
    #pragma unroll
    for (int off = 32; off > 0; off >>= 1) {
        float m2  = __shfl_down(m,   off);
        float c2  = __shfl_down(cnt, off);
        float si2 = __shfl_down(si,  off);
        float sj2 = __shfl_down(sj,  off);
        bool gt = m2 > m, eq = m2 == m;
        cnt = gt ? c2  : (cnt + (eq ? c2  : 0.0f));
        si  = gt ? si2 : (si  + (eq ? si2 : 0.0f));
        sj  = gt ? sj2 : (sj  + (eq ? sj2 : 0.0f));
        m   = fmaxf(m, m2);
    }
    __shared__ float sm[7], sc[7], ssi[7], ssj[7];
    const int lane = tid & 63, wid = tid >> 6;
    if (lane == 0) { sm[wid] = m; sc[wid] = cnt; ssi[wid] = si; ssj[wid] = sj; }
    __syncthreads();
    if (tid == 0) {
        float M = sm[0], C = sc[0], SI = ssi[0], SJ = ssj[0];
        #pragma unroll
        for (int w = 1; w < 7; ++w) {
            float mw = sm[w];
            bool gt = mw > M, eq = mw == M;
            C  = gt ? sc[w]  : (C  + (eq ? sc[w]  : 0.0f));
            SI = gt ? ssi[w] : (SI + (eq ? ssi[w] : 0.0f));
            SJ = gt ? ssj[w] : (SJ + (eq ? ssj[w] : 0.0f));
            M  = fmaxf(M, mw);
        }
        stats[blk] = make_float4(M, C, SI, SJ);
    }
}

__global__ __launch_bounds__(NTHR) void bce_kernel(
    const float* __restrict__ input,
    const float* __restrict__ target,
    const float4* __restrict__ stats,
    float* __restrict__ out,
    float inv_total)
{
    const int blk  = blockIdx.x;
    const int b    = blk >> 2;
    const int part = blk & 3;
    const int tid  = threadIdx.x;

    // Merge this image's 4 stat tuples (exact tie semantics) -> centroid x,y.
    __shared__ float sxy[2];
    if (tid == 0) {
        float4 s0 = stats[b * 4];
        float M = s0.x, C = s0.y, SI = s0.z, SJ = s0.w;
        #pragma unroll
        for (int t = 1; t < 4; ++t) {
            float4 s = stats[b * 4 + t];
            bool gt = s.x > M, eq = s.x == M;
            C  = gt ? s.y : (C  + (eq ? s.y : 0.0f));
            SI = gt ? s.z : (SI + (eq ? s.z : 0.0f));
            SJ = gt ? s.w : (SJ + (eq ? s.w : 0.0f));
            M  = fmaxf(M, s.x);
        }
        sxy[0] = SI / C;
        sxy[1] = SJ / C;
    }
    __syncthreads();
    const float x = sxy[0], y = sxy[1];

    const float4* __restrict__ t4 = (const float4*)(target + (size_t)b * WW);
    const float4* __restrict__ p4 = (const float4*)(input  + (size_t)b * WW);
    const int qbase = part * QPB;
    const float Kc = -(float)WIMG * LN2;    // fold -ln2 into the weight

    float acc = 0.0f;
    #pragma unroll
    for (int it = 0; it < QPB / NTHR; ++it) {
        int q  = qbase + it * NTHR + tid;
        float4 tv = t4[q];
        float4 pv = p4[q];
        int i  = q / 56;
        int j0 = (q - i * 56) * 4;
        float di  = (float)i - x;
        float di2 = di * di;
        float tt[4] = {tv.x, tv.y, tv.z, tv.w};
        float pp[4] = {pv.x, pv.y, pv.z, pv.w};
        #pragma unroll
        for (int k = 0; k < 4; ++k) {
            float dj = (float)(j0 + k) - y;
            float s  = __builtin_amdgcn_sqrtf(di2 + dj * dj);
            float wf = Kc * __builtin_amdgcn_rcpf(s + 1.0f);   // -224*ln2/(sqrt+1)
            float p = pp[k], t = tt[k];
            float lp2  = fmaxf(__builtin_amdgcn_logf(p),        CLAMP2);
            float l1p2 = fmaxf(__builtin_amdgcn_logf(1.0f - p), CLAMP2);
            acc += wf * (l1p2 + t * (lp2 - l1p2));
        }
    }
    #pragma unroll
    for (int off = 32; off > 0; off >>= 1) acc += __shfl_down(acc, off);
    __shared__ float sred[7];
    const int lane = tid & 63, wid = tid >> 6;
    if (lane == 0) sred[wid] = acc;
    __syncthreads();
    if (tid == 0) {
        float ssum = 0.0f;
        #pragma unroll
        for (int w = 0; w < 7; ++w) ssum += sred[w];
        atomicAdd(out, ssum * inv_total);
    }
}

extern "C" void kernel_launch(void* const* d_in, const int* in_sizes, int n_in,
                              void* d_out, int out_size, void* d_ws, size_t ws_size,
                              hipStream_t stream) {
    const float* input  = (const float*)d_in[0];
    const float* target = (const float*)d_in[1];
    float* out = (float*)d_out;
    float4* stats = (float4*)d_ws;           // 1024 float4

    hipMemsetAsync(out, 0, sizeof(float), stream);
    stats_kernel<<<NBLK, NTHR, 0, stream>>>(target, stats);
    const float inv_total = 1.0f / (256.0f * 224.0f * 224.0f);
    bce_kernel<<<NBLK, NTHR, 0, stream>>>(input, target, stats, out, inv_total);
}